// Round 2
// 428.050 us; speedup vs baseline: 1.0254x; 1.0254x over previous
//
#include <hip/hip_runtime.h>

// HadamardTrustQuantizer forward:
//   out = H128( clip(round(H128(x)/step), -7, 7) * step ), step = ALPHA*rms/7
// STE forward value is exactly xq (trust mask cancels in the forward pass).
//
// R4 = R3 with the nontemporal builtin applied to a native ext_vector_type
// (clang rejects HIP_vector_type<float,4> there).
//
// Block-local register layout. Lane l owns, for c=0..3, s=0..3, the
// float4 at  row*4096 + c*1024 + (l>>3)*128 + s*32 + (l&7)*4.
// Register i = c*16 + s*4 + m  <->  within-block index w = s*32 + (l&7)*4 + m.
// FWHT-128 stages over w:
//   strides 1,2   -> inside each float4 (radix-4, in-register)
//   strides 4,8   -> lane xor 1,2  (DPP quad_perm, VALU-rate)
//   stride  16    -> lane xor 4    (ds_swizzle, the ONLY LDS-pipe stage)
//   strides 32,64 -> register pairs i^4, i^8 (pure add/sub, no permute)
// Quantize uses one wave-uniform IEEE divide + Markstein-refined reciprocal
// multiply. Final 1/128 folded into the dequant scale (exact pow2).

#define HTQ_ALPHA 2.5139f
#define HTQ_QMAX  7.0f

typedef float vfloat4 __attribute__((ext_vector_type(4)));

template <int CTRL>
__device__ __forceinline__ float dpp_perm(float f) {
    int r = __builtin_amdgcn_update_dpp(__float_as_int(f), __float_as_int(f),
                                        CTRL, 0xF, 0xF, true);
    return __int_as_float(r);
}

template <int MASK>
__device__ __forceinline__ float swz_xor(float f) {
    int r = __builtin_amdgcn_ds_swizzle(__float_as_int(f), (MASK << 10) | 0x1F);
    return __int_as_float(r);
}

// cross-lane butterfly stage: v = (lane&BIT) ? partner - v : v + partner
#define CROSS_STAGE(GETP, BIT)                                   \
    {                                                            \
        const float sg = (lane & (BIT)) ? -1.0f : 1.0f;          \
        _Pragma("unroll")                                        \
        for (int i = 0; i < 64; ++i) {                           \
            float p = GETP(v[i]);                                \
            v[i] = fmaf(sg, v[i], p);                            \
        }                                                        \
    }

__device__ __forceinline__ void fwht128(float v[64], int lane) {
    // strides 1,2: radix-4 inside each float4 register group
#pragma unroll
    for (int g = 0; g < 16; ++g) {
        float a0 = v[4 * g], a1 = v[4 * g + 1], a2 = v[4 * g + 2], a3 = v[4 * g + 3];
        float t0 = a0 + a1, t1 = a0 - a1, t2 = a2 + a3, t3 = a2 - a3;
        v[4 * g]     = t0 + t2;
        v[4 * g + 1] = t1 + t3;
        v[4 * g + 2] = t0 - t2;
        v[4 * g + 3] = t1 - t3;
    }
    // strides 4,8,16 -> lane xor 1,2,4
    CROSS_STAGE(dpp_perm<0xB1>, 1)   // quad_perm [1,0,3,2]
    CROSS_STAGE(dpp_perm<0x4E>, 2)   // quad_perm [2,3,0,1]
    CROSS_STAGE(swz_xor<4>, 4)       // ds_swizzle xor-4
    // stride 32 -> register pairs (i, i+4): pure add/sub
#pragma unroll
    for (int i = 0; i < 64; ++i) {
        if (i & 4) continue;         // folds at compile time (full unroll)
        float a = v[i], b = v[i + 4];
        v[i] = a + b;
        v[i + 4] = a - b;
    }
    // stride 64 -> register pairs (i, i+8): pure add/sub
#pragma unroll
    for (int i = 0; i < 64; ++i) {
        if (i & 8) continue;
        float a = v[i], b = v[i + 8];
        v[i] = a + b;
        v[i + 8] = a - b;
    }
}

__global__ __launch_bounds__(256) void htq_kernel(const float* __restrict__ x,
                                                  float* __restrict__ out) {
    const int gid  = blockIdx.x * 256 + threadIdx.x;
    const int row  = gid >> 6;
    const int lane = threadIdx.x & 63;
    const int oct  = lane >> 3;   // which 128-block inside a 1024-chunk
    const int sub  = lane & 7;    // which 16B slot inside the 32-elem strip

    const size_t base = (size_t)row * 4096 + (size_t)(oct * 128 + sub * 4);

    float v[64];
    vfloat4* v4 = reinterpret_cast<vfloat4*>(v);
    const vfloat4* g4 = reinterpret_cast<const vfloat4*>(x + base);
    // per wave, each load t covers 8 segments of 128 contiguous bytes (full
    // cache lines), stride 512B -> fully coalesced at line granularity
#pragma unroll
    for (int t = 0; t < 16; ++t)
        v4[t] = __builtin_nontemporal_load(&g4[(t >> 2) * 256 + (t & 3) * 8]);

    fwht128(v, lane);   // y = sqrt(128) * x_h  (unnormalized)

    // row RMS over all 4096 elements (whole wave holds one row)
    float ss = 0.0f;
#pragma unroll
    for (int i = 0; i < 64; ++i) ss = fmaf(v[i], v[i], ss);
#pragma unroll
    for (int m = 1; m < 64; m <<= 1) ss += __shfl_xor(ss, m, 64);

    float std_y = sqrtf(ss * (1.0f / 4096.0f));       // = sqrt(128)*std_ref
    std_y = fmaxf(std_y, 1.1313708499e-7f);           // 1e-8 * sqrt(128)
    const float step  = (HTQ_ALPHA * std_y) / HTQ_QMAX;
    const float inv   = 1.0f / step;                  // one IEEE div, wave-uniform
    const float step2 = step * 0.0078125f;            // fold final 1/128 (exact pow2)

    // quantize: Markstein-refined reciprocal multiply tracks the correctly-
    // rounded quotient to <1 ulp, so rint matches the exact-div path except
    // on ~1-ulp-from-half ties.
#pragma unroll
    for (int i = 0; i < 64; ++i) {
        const float xv = v[i];
        float q0 = xv * inv;
        float rr = fmaf(-q0, step, xv);   // residual, exact via fma
        float q  = fmaf(rr, inv, q0);     // refined quotient
        float r  = rintf(q);
        r = fminf(fmaxf(r, -HTQ_QMAX), HTQ_QMAX);
        v[i] = r * step2;                 // dequant with 1/128 pre-folded
    }

    fwht128(v, lane);   // back-rotate (unnormalized); 1/128 already applied

    vfloat4* o4 = reinterpret_cast<vfloat4*>(out + base);
#pragma unroll
    for (int t = 0; t < 16; ++t)
        __builtin_nontemporal_store(v4[t], &o4[(t >> 2) * 256 + (t & 3) * 8]);
}

extern "C" void kernel_launch(void* const* d_in, const int* in_sizes, int n_in,
                              void* d_out, int out_size, void* d_ws, size_t ws_size,
                              hipStream_t stream) {
    const float* x = (const float*)d_in[0];
    float* out = (float*)d_out;

    const int n    = in_sizes[0];     // 4*4096*4096
    const int rows = n / 4096;        // one wave per 4096-elem row
    const int blocks = (rows * 64) / 256;

    hipLaunchKernelGGL(htq_kernel, dim3(blocks), dim3(256), 0, stream, x, out);
}

// Round 3
// 426.666 us; speedup vs baseline: 1.0288x; 1.0032x over previous
//
#include <hip/hip_runtime.h>

// HadamardTrustQuantizer forward:
//   out = H128( clip(round(H128(x)/step), -7, 7) * step ), step = ALPHA*rms/7
// STE forward value is exactly xq (trust mask cancels in the forward pass).
//
// R5: half-row waves + 4-lanes-per-128-block register layout.
//  - One wave owns 2048 elements (v[32]); a block of 4 waves covers 2 rows.
//    VGPR ~50 -> __launch_bounds__(256,8) -> 8 waves/SIMD (was ~5). Row RMS
//    needs one tiny LDS exchange between the two waves of a row.
//  - Lane l owns ALL 32 elements of 128-block (l>>2):
//       w = s*16 + (l&3)*4 + m,  register i = s*4 + m  (s=0..7, m=0..3)
//    FWHT-128 stages over w:
//       strides 1,2    -> inside each float4 (radix-4, in-register)
//       strides 4,8    -> lane xor 1,2 (DPP quad_perm, VALU-rate)
//       strides 16,32,64 -> register pairs s^1, s^2, s^4 (pure add/sub)
//    => ZERO ds_swizzle in the FWHT (R4 had 64 DS ops/thread); DS pipe is
//    only touched by the 2-float RMS exchange.
//  - Stage order over distinct index bits commutes -> bit-identical to R4.
// Quantize: one wave-uniform IEEE divide + Markstein-refined reciprocal
// multiply. Final 1/128 folded into the dequant scale (exact pow2).
// Loads/stores nontemporal: pure streaming, zero reuse.

#define HTQ_ALPHA 2.5139f
#define HTQ_QMAX  7.0f

typedef float vfloat4 __attribute__((ext_vector_type(4)));

template <int CTRL>
__device__ __forceinline__ float dpp_perm(float f) {
    int r = __builtin_amdgcn_update_dpp(__float_as_int(f), __float_as_int(f),
                                        CTRL, 0xF, 0xF, true);
    return __int_as_float(r);
}

// cross-lane butterfly stage: v = (lane&BIT) ? partner - v : v + partner
#define CROSS_STAGE(GETP, BIT)                                   \
    {                                                            \
        const float sg = (lane & (BIT)) ? -1.0f : 1.0f;          \
        _Pragma("unroll")                                        \
        for (int i = 0; i < 32; ++i) {                           \
            float p = GETP(v[i]);                                \
            v[i] = fmaf(sg, v[i], p);                            \
        }                                                        \
    }

__device__ __forceinline__ void fwht128(float v[32], int lane) {
    // strides 1,2: radix-4 inside each float4 register group
#pragma unroll
    for (int g = 0; g < 8; ++g) {
        float a0 = v[4 * g], a1 = v[4 * g + 1], a2 = v[4 * g + 2], a3 = v[4 * g + 3];
        float t0 = a0 + a1, t1 = a0 - a1, t2 = a2 + a3, t3 = a2 - a3;
        v[4 * g]     = t0 + t2;
        v[4 * g + 1] = t1 + t3;
        v[4 * g + 2] = t0 - t2;
        v[4 * g + 3] = t1 - t3;
    }
    // strides 4,8 -> lane xor 1,2 (DPP)
    CROSS_STAGE(dpp_perm<0xB1>, 1)   // quad_perm [1,0,3,2]
    CROSS_STAGE(dpp_perm<0x4E>, 2)   // quad_perm [2,3,0,1]
    // stride 16 -> register pairs (i, i+4)
#pragma unroll
    for (int i = 0; i < 32; ++i) {
        if (i & 4) continue;         // folds at compile time (full unroll)
        float a = v[i], b = v[i + 4];
        v[i] = a + b;
        v[i + 4] = a - b;
    }
    // stride 32 -> register pairs (i, i+8)
#pragma unroll
    for (int i = 0; i < 32; ++i) {
        if (i & 8) continue;
        float a = v[i], b = v[i + 8];
        v[i] = a + b;
        v[i + 8] = a - b;
    }
    // stride 64 -> register pairs (i, i+16)
#pragma unroll
    for (int i = 0; i < 32; ++i) {
        if (i & 16) continue;
        float a = v[i], b = v[i + 16];
        v[i] = a + b;
        v[i + 16] = a - b;
    }
}

__global__ __launch_bounds__(256, 8) void htq_kernel(const float* __restrict__ x,
                                                     float* __restrict__ out) {
    const int wv   = threadIdx.x >> 6;         // wave in block, 0..3
    const int lane = threadIdx.x & 63;
    const int gw   = blockIdx.x * 4 + wv;      // global wave id
    const int row  = gw >> 1;                  // 2 waves per 4096-elem row
    const int half = gw & 1;
    const int blk  = lane >> 2;                // 16 blocks of 128 per half-row
    const int sub  = lane & 3;

    const size_t base = (size_t)row * 4096 + (size_t)half * 2048
                      + (size_t)(blk * 128 + sub * 4);

    float v[32];
    vfloat4* v4 = reinterpret_cast<vfloat4*>(v);
    const vfloat4* g4 = reinterpret_cast<const vfloat4*>(x + base);
    // per wave instr: 16 segments x 64B at 512B stride; s and s^1 cover
    // complementary halves of each 128B line -> lines fully consumed
#pragma unroll
    for (int s = 0; s < 8; ++s)
        v4[s] = __builtin_nontemporal_load(&g4[s * 4]);

    fwht128(v, lane);   // y = sqrt(128) * x_h  (unnormalized)

    // row RMS: per-wave partial over 2048 elems, then combine across the pair
    float ss = 0.0f;
#pragma unroll
    for (int i = 0; i < 32; ++i) ss = fmaf(v[i], v[i], ss);
#pragma unroll
    for (int m = 1; m < 64; m <<= 1) ss += __shfl_xor(ss, m, 64);

    __shared__ float red[4];
    if (lane == 0) red[wv] = ss;
    __syncthreads();
    ss = red[wv] + red[wv ^ 1];                // full-row sum of squares

    float std_y = sqrtf(ss * (1.0f / 4096.0f));       // = sqrt(128)*std_ref
    std_y = fmaxf(std_y, 1.1313708499e-7f);           // 1e-8 * sqrt(128)
    const float step  = (HTQ_ALPHA * std_y) / HTQ_QMAX;
    const float inv   = 1.0f / step;                  // one IEEE div, wave-uniform
    const float step2 = step * 0.0078125f;            // fold final 1/128 (exact pow2)

    // quantize: Markstein-refined reciprocal multiply tracks the correctly-
    // rounded quotient to <1 ulp, so rint matches the exact-div path except
    // on ~1-ulp-from-half ties.
#pragma unroll
    for (int i = 0; i < 32; ++i) {
        const float xv = v[i];
        float q0 = xv * inv;
        float rr = fmaf(-q0, step, xv);   // residual, exact via fma
        float q  = fmaf(rr, inv, q0);     // refined quotient
        float r  = rintf(q);
        r = fminf(fmaxf(r, -HTQ_QMAX), HTQ_QMAX);
        v[i] = r * step2;                 // dequant with 1/128 pre-folded
    }

    fwht128(v, lane);   // back-rotate (unnormalized); 1/128 already applied

    vfloat4* o4 = reinterpret_cast<vfloat4*>(out + base);
#pragma unroll
    for (int s = 0; s < 8; ++s)
        __builtin_nontemporal_store(v4[s], &o4[s * 4]);
}

extern "C" void kernel_launch(void* const* d_in, const int* in_sizes, int n_in,
                              void* d_out, int out_size, void* d_ws, size_t ws_size,
                              hipStream_t stream) {
    const float* x = (const float*)d_in[0];
    float* out = (float*)d_out;

    const int n    = in_sizes[0];     // 4*4096*4096
    const int rows = n / 4096;        // 2 waves per row, 4 waves per block
    const int blocks = rows / 2;

    hipLaunchKernelGGL(htq_kernel, dim3(blocks), dim3(256), 0, stream, x, out);
}